// Round 5
// baseline (43806.436 us; speedup 1.0000x reference)
//
#include <hip/hip_runtime.h>
#include <cstdint>

// Problem constants: D=512, H=2048, T=2048, O=512, 4H=8192.
#define H_DIM 2048
#define H4_DIM 8192
#define T_LEN 2048
#define NREP 8           // slot replicas (per-XCD contention spreading)

typedef unsigned long long u64;
typedef __attribute__((ext_vector_type(2))) float v2f;

__device__ __forceinline__ float sigmoid_f(float x) {
  return 1.0f / (1.0f + __expf(-x));
}
__device__ __forceinline__ float tanh_f(float x) {
  float ax = fabsf(x);
  float e = __expf(-2.0f * ax);
  float r = (1.0f - e) / (1.0f + e);
  return copysignf(r, x);
}

// ---- fused 2-layer persistent LSTM pipeline, r10 ----------------------------
// History: r5=11.2ms baseline (2x lstm_rec @5.1ms). r6 flag-split: +hop,
// regressed. r7/r8 barrier restructure: 2x regression (pinned scheduling).
// r9 waves_per_eu: no-op (weights already AGPR-resident; VGPR_Count counts
// arch only). Conclusion: per-step latency (~6000cy = store visibility +
// MALL poll + straggler max over 256 blocks) resisted 3 attacks. r10 attacks
// the STEP COUNT instead: layer-1 step t needs only h0(t+1),h1(t) -> run both
// layers in ONE kernel as a 1-deep pipeline. Rounds: 4096 -> 2049.
//   - every block holds register slices of Whh0, Wih1, Whh1: 384 floats/lane
//     (<=256 arch + <=256 acc unified file; 2 waves/SIMD -> fits).
//   - round r: layer0 computes h0(r+1) from h0(r),xp0(r) [r<T];
//              layer1 computes h1(r) from h1(r-1),h0(r), with Wih1@h0
//              accumulated into the same dot as Whh1@h1 (bias in regs).
//              Second GEMM + ys buffer eliminated.
//   - exchange protocol is r5's proven one, duplicated for h0/h1 slot arrays:
//     tagged u64 slots, NREP replicas, s_sleep(1) backoff poll, two full
//     __syncthreads per round. Tags 1..2049 never match 0xAAAAAAAA poison;
//     tag loop is the correctness net. Same 2-round slot-reuse separation
//     proof as r5 (a producer reaches round r+2 only after every block
//     consumed round r+1 tags).
//   - round 0 publishes h0(1) and h1(0)=0 (tag 1); round T publishes only
//     h1(T) (tag T+1). fc reads slots1 replica0 parity1 (=(T+1)&1).
__global__ __launch_bounds__(512, 2) void lstm_fused(
    const float* __restrict__ Whh0,  // (8192, 2048)
    const float* __restrict__ Wih1,  // (8192, 2048)
    const float* __restrict__ Whh1,  // (8192, 2048)
    const float* __restrict__ xp,    // (T, 8192) layer-0 x-projection+biases
    const float* __restrict__ bih1,  // (8192,)
    const float* __restrict__ bhh1,  // (8192,)
    u64* __restrict__ slots0,        // NREP * 2 * 2048 tagged h0
    u64* __restrict__ slots1,        // NREP * 2 * 2048 tagged h1
    int T)
{
  __shared__ float hl0[H_DIM];
  __shared__ float hl1[H_DIM];
  const int g = blockIdx.x;
  const int tid = threadIdx.x;
  const int w = tid >> 6;
  const int l = tid & 63;
  const int j = g * 8 + w;
  const int rep = g & (NREP - 1);

  // one-time weight loads (each element read exactly once grid-wide),
  // packed as float2 for v_pk_fma_f32. 192 v2f = 384 regs/lane (arch+acc).
  v2f w0r[64], wi1r[64], wh1r[64];
  #pragma unroll
  for (int q = 0; q < 4; ++q) {
    const size_t row = (size_t)(j + q * H_DIM) * H_DIM + l * 4;
    const float* p0 = Whh0 + row;
    const float* p1 = Wih1 + row;
    const float* p2 = Whh1 + row;
    #pragma unroll
    for (int k = 0; k < 8; ++k) {
      float4 v0 = *(const float4*)(p0 + 256 * k);
      float4 v1 = *(const float4*)(p1 + 256 * k);
      float4 v2 = *(const float4*)(p2 + 256 * k);
      w0r [q * 16 + k * 2 + 0] = (v2f){v0.x, v0.y};
      w0r [q * 16 + k * 2 + 1] = (v2f){v0.z, v0.w};
      wi1r[q * 16 + k * 2 + 0] = (v2f){v1.x, v1.y};
      wi1r[q * 16 + k * 2 + 1] = (v2f){v1.z, v1.w};
      wh1r[q * 16 + k * 2 + 0] = (v2f){v2.x, v2.y};
      wh1r[q * 16 + k * 2 + 1] = (v2f){v2.z, v2.w};
    }
  }
  // layer-1 combined bias (wave-uniform scalars)
  const float bi1_0 = bih1[j]             + bhh1[j];
  const float bi1_1 = bih1[j + H_DIM]     + bhh1[j + H_DIM];
  const float bi1_2 = bih1[j + 2 * H_DIM] + bhh1[j + 2 * H_DIM];
  const float bi1_3 = bih1[j + 3 * H_DIM] + bhh1[j + 3 * H_DIM];

  float c0 = 0.0f, c1 = 0.0f;

  for (int r = 0; r <= T; ++r) {
    // prefetch layer-0 x-projection for this round (lanes 0..7)
    float xq0 = 0.f, xq1 = 0.f, xq2 = 0.f, xq3 = 0.f;
    if (r < T && l < NREP) {
      const float* xrow = xp + (size_t)r * H4_DIM + j;
      xq0 = xrow[0];
      xq1 = xrow[H_DIM];
      xq2 = xrow[2 * H_DIM];
      xq3 = xrow[3 * H_DIM];
    }

    if (r == 0) {
      ((float4*)hl0)[tid] = make_float4(0.f, 0.f, 0.f, 0.f);
      ((float4*)hl1)[tid] = make_float4(0.f, 0.f, 0.f, 0.f);
    } else {
      // joint poll for h0(r) and h1(r-1), both tagged r (published at the
      // end of round r-1). s_sleep backoff = congestion control (r7 lesson).
      const u64* S0 = slots0 + (size_t)(rep * 2 + (r & 1)) * H_DIM + tid;
      const u64* S1 = slots1 + (size_t)(rep * 2 + (r & 1)) * H_DIM + tid;
      u64 u0, u1, u2, u3, q0, q1, q2, q3;
      for (;;) {
        u0 = __hip_atomic_load(S0,        __ATOMIC_RELAXED, __HIP_MEMORY_SCOPE_AGENT);
        u1 = __hip_atomic_load(S0 + 512,  __ATOMIC_RELAXED, __HIP_MEMORY_SCOPE_AGENT);
        u2 = __hip_atomic_load(S0 + 1024, __ATOMIC_RELAXED, __HIP_MEMORY_SCOPE_AGENT);
        u3 = __hip_atomic_load(S0 + 1536, __ATOMIC_RELAXED, __HIP_MEMORY_SCOPE_AGENT);
        q0 = __hip_atomic_load(S1,        __ATOMIC_RELAXED, __HIP_MEMORY_SCOPE_AGENT);
        q1 = __hip_atomic_load(S1 + 512,  __ATOMIC_RELAXED, __HIP_MEMORY_SCOPE_AGENT);
        q2 = __hip_atomic_load(S1 + 1024, __ATOMIC_RELAXED, __HIP_MEMORY_SCOPE_AGENT);
        q3 = __hip_atomic_load(S1 + 1536, __ATOMIC_RELAXED, __HIP_MEMORY_SCOPE_AGENT);
        bool ok = ((unsigned)(u0 >> 32) == (unsigned)r) &
                  ((unsigned)(u1 >> 32) == (unsigned)r) &
                  ((unsigned)(u2 >> 32) == (unsigned)r) &
                  ((unsigned)(u3 >> 32) == (unsigned)r) &
                  ((unsigned)(q0 >> 32) == (unsigned)r) &
                  ((unsigned)(q1 >> 32) == (unsigned)r) &
                  ((unsigned)(q2 >> 32) == (unsigned)r) &
                  ((unsigned)(q3 >> 32) == (unsigned)r);
        if (__all(ok)) break;
        __builtin_amdgcn_s_sleep(1);
      }
      hl0[tid]        = __uint_as_float((unsigned)u0);
      hl0[tid + 512]  = __uint_as_float((unsigned)u1);
      hl0[tid + 1024] = __uint_as_float((unsigned)u2);
      hl0[tid + 1536] = __uint_as_float((unsigned)u3);
      hl1[tid]        = __uint_as_float((unsigned)q0);
      hl1[tid + 512]  = __uint_as_float((unsigned)q1);
      hl1[tid + 1024] = __uint_as_float((unsigned)q2);
      hl1[tid + 1536] = __uint_as_float((unsigned)q3);
    }
    __syncthreads();

    // fused matvecs: 192 v_pk_fma per thread
    //   A* = Whh0 @ h0(r)          (layer-0 gates)
    //   B* = Wih1 @ h0(r) + Whh1 @ h1(r-1)   (layer-1 gates)
    v2f A0 = {0.f, 0.f}, A1 = {0.f, 0.f}, A2 = {0.f, 0.f}, A3 = {0.f, 0.f};
    v2f B0 = {0.f, 0.f}, B1 = {0.f, 0.f}, B2 = {0.f, 0.f}, B3 = {0.f, 0.f};
    #pragma unroll
    for (int k = 0; k < 8; ++k) {
      float4 h04 = ((const float4*)hl0)[l + 64 * k];
      float4 h14 = ((const float4*)hl1)[l + 64 * k];
      v2f h0lo = {h04.x, h04.y}, h0hi = {h04.z, h04.w};
      v2f h1lo = {h14.x, h14.y}, h1hi = {h14.z, h14.w};
      A0 = __builtin_elementwise_fma(w0r[0 + k * 2],  h0lo, A0);
      A0 = __builtin_elementwise_fma(w0r[1 + k * 2],  h0hi, A0);
      A1 = __builtin_elementwise_fma(w0r[16 + k * 2], h0lo, A1);
      A1 = __builtin_elementwise_fma(w0r[17 + k * 2], h0hi, A1);
      A2 = __builtin_elementwise_fma(w0r[32 + k * 2], h0lo, A2);
      A2 = __builtin_elementwise_fma(w0r[33 + k * 2], h0hi, A2);
      A3 = __builtin_elementwise_fma(w0r[48 + k * 2], h0lo, A3);
      A3 = __builtin_elementwise_fma(w0r[49 + k * 2], h0hi, A3);

      B0 = __builtin_elementwise_fma(wi1r[0 + k * 2],  h0lo, B0);
      B0 = __builtin_elementwise_fma(wi1r[1 + k * 2],  h0hi, B0);
      B1 = __builtin_elementwise_fma(wi1r[16 + k * 2], h0lo, B1);
      B1 = __builtin_elementwise_fma(wi1r[17 + k * 2], h0hi, B1);
      B2 = __builtin_elementwise_fma(wi1r[32 + k * 2], h0lo, B2);
      B2 = __builtin_elementwise_fma(wi1r[33 + k * 2], h0hi, B2);
      B3 = __builtin_elementwise_fma(wi1r[48 + k * 2], h0lo, B3);
      B3 = __builtin_elementwise_fma(wi1r[49 + k * 2], h0hi, B3);

      B0 = __builtin_elementwise_fma(wh1r[0 + k * 2],  h1lo, B0);
      B0 = __builtin_elementwise_fma(wh1r[1 + k * 2],  h1hi, B0);
      B1 = __builtin_elementwise_fma(wh1r[16 + k * 2], h1lo, B1);
      B1 = __builtin_elementwise_fma(wh1r[17 + k * 2], h1hi, B1);
      B2 = __builtin_elementwise_fma(wh1r[32 + k * 2], h1lo, B2);
      B2 = __builtin_elementwise_fma(wh1r[33 + k * 2], h1hi, B2);
      B3 = __builtin_elementwise_fma(wh1r[48 + k * 2], h1lo, B3);
      B3 = __builtin_elementwise_fma(wh1r[49 + k * 2], h1hi, B3);
    }
    float a0 = A0.x + A0.y, a1 = A1.x + A1.y;
    float a2 = A2.x + A2.y, a3 = A3.x + A3.y;
    float b0 = B0.x + B0.y, b1 = B1.x + B1.y;
    float b2 = B2.x + B2.y, b3 = B3.x + B3.y;

    // 64-lane butterfly ALLreduce, 8 values
    #pragma unroll
    for (int off = 32; off; off >>= 1) {
      a0 += __shfl_xor(a0, off);
      a1 += __shfl_xor(a1, off);
      a2 += __shfl_xor(a2, off);
      a3 += __shfl_xor(a3, off);
      b0 += __shfl_xor(b0, off);
      b1 += __shfl_xor(b1, off);
      b2 += __shfl_xor(b2, off);
      b3 += __shfl_xor(b3, off);
    }

    // layer-0 gates (real xq only on lanes 0..7, which publish)
    float h0_ = 0.f;
    if (r < T) {
      float i_ = sigmoid_f(a0 + xq0);
      float f_ = sigmoid_f(a1 + xq1);
      float g_ = tanh_f(a2 + xq2);
      float o_ = sigmoid_f(a3 + xq3);
      c0 = f_ * c0 + i_ * g_;
      h0_ = o_ * tanh_f(c0);
    }
    // layer-1 gates (bias broadcast: identical on all lanes)
    float h1_ = 0.f;
    if (r >= 1) {
      float i_ = sigmoid_f(b0 + bi1_0);
      float f_ = sigmoid_f(b1 + bi1_1);
      float g_ = tanh_f(b2 + bi1_2);
      float o_ = sigmoid_f(b3 + bi1_3);
      c1 = f_ * c1 + i_ * g_;
      h1_ = o_ * tanh_f(c1);
    }

    if (l < NREP) {
      const size_t soff = (size_t)(l * 2 + ((r + 1) & 1)) * H_DIM + j;
      const u64 tagw = (u64)(unsigned)(r + 1) << 32;
      if (r < T) {
        union { float f; unsigned u; } cv; cv.f = h0_;
        __hip_atomic_store(slots0 + soff, tagw | (u64)cv.u,
                           __ATOMIC_RELAXED, __HIP_MEMORY_SCOPE_AGENT);
      }
      union { float f; unsigned u; } dv; dv.f = h1_;
      __hip_atomic_store(slots1 + soff, tagw | (u64)dv.u,
                         __ATOMIC_RELAXED, __HIP_MEMORY_SCOPE_AGENT);
    }
    // all waves must finish reading hl0/hl1 before next round's poll
    // overwrites them
    __syncthreads();
  }
}

// ---- fp32 GEMM: C[M][N] = A[M][K] @ W[N][K]^T + b0[n] + b1[n] ----
// 128x128 tile, 256 threads, 8x8 microtile, BK=8. (layer-0 xp only)
__global__ __launch_bounds__(256) void gemm_bt_bias(
    const float* __restrict__ A, const float* __restrict__ W,
    const float* __restrict__ b0, const float* __restrict__ b1,
    float* __restrict__ C, int M, int N, int K)
{
  __shared__ float As[8][128];
  __shared__ float Bs[8][128];
  const int tid = threadIdx.x;
  const int n0 = blockIdx.x * 128;
  const int m0 = blockIdx.y * 128;
  const int tx = tid & 15;   // n direction
  const int ty = tid >> 4;   // m direction
  const int lr = tid >> 1;   // loader row 0..127
  const int lk = (tid & 1) * 4;
  const float* Ap = A + (size_t)(m0 + lr) * K + lk;
  const float* Wp = W + (size_t)(n0 + lr) * K + lk;

  float acc[8][8];
  #pragma unroll
  for (int i = 0; i < 8; ++i)
    #pragma unroll
    for (int jj = 0; jj < 8; ++jj) acc[i][jj] = 0.f;

  for (int kt = 0; kt < K; kt += 8) {
    float4 av = *(const float4*)(Ap + kt);
    float4 wv = *(const float4*)(Wp + kt);
    __syncthreads();
    As[lk + 0][lr] = av.x; As[lk + 1][lr] = av.y;
    As[lk + 2][lr] = av.z; As[lk + 3][lr] = av.w;
    Bs[lk + 0][lr] = wv.x; Bs[lk + 1][lr] = wv.y;
    Bs[lk + 2][lr] = wv.z; Bs[lk + 3][lr] = wv.w;
    __syncthreads();
    #pragma unroll
    for (int k = 0; k < 8; ++k) {
      float a[8], b[8];
      *(float4*)&a[0] = *(const float4*)&As[k][ty * 8];
      *(float4*)&a[4] = *(const float4*)&As[k][ty * 8 + 4];
      *(float4*)&b[0] = *(const float4*)&Bs[k][tx * 8];
      *(float4*)&b[4] = *(const float4*)&Bs[k][tx * 8 + 4];
      #pragma unroll
      for (int i = 0; i < 8; ++i)
        #pragma unroll
        for (int jj = 0; jj < 8; ++jj)
          acc[i][jj] = fmaf(a[i], b[jj], acc[i][jj]);
    }
  }

  const int n = n0 + tx * 8;
  float bias[8];
  #pragma unroll
  for (int jj = 0; jj < 8; ++jj)
    bias[jj] = b0[n + jj] + (b1 ? b1[n + jj] : 0.f);
  #pragma unroll
  for (int i = 0; i < 8; ++i) {
    float* crow = C + (size_t)(m0 + ty * 8 + i) * N + n;
    float4 v0 = make_float4(acc[i][0] + bias[0], acc[i][1] + bias[1],
                            acc[i][2] + bias[2], acc[i][3] + bias[3]);
    float4 v1 = make_float4(acc[i][4] + bias[4], acc[i][5] + bias[5],
                            acc[i][6] + bias[6], acc[i][7] + bias[7]);
    *(float4*)crow = v0;
    *(float4*)(crow + 4) = v1;
  }
}

// ---- final FC: out[o] = dot(h_last, fc_w[o]) + fc_b[o], one wave/output ----
// hslots points at slots1 replica 0, parity 1 (h1(T), tag T+1).
__global__ void fc_kernel(const u64* __restrict__ hslots,
                          const float* __restrict__ Wf,
                          const float* __restrict__ bf,
                          float* __restrict__ out)
{
  const int o = blockIdx.x;
  const int l = threadIdx.x;
  const float* wr = Wf + (size_t)o * H_DIM;
  float s = 0.f;
  #pragma unroll
  for (int k = 0; k < 32; ++k) {
    union { unsigned u; float f; } cv;
    cv.u = (unsigned)hslots[l + 64 * k];
    s = fmaf(wr[l + 64 * k], cv.f, s);
  }
  #pragma unroll
  for (int off = 32; off; off >>= 1) s += __shfl_xor(s, off);
  if (l == 0) out[o] = s + bf[o];
}

extern "C" void kernel_launch(void* const* d_in, const int* in_sizes, int n_in,
                              void* d_out, int out_size, void* d_ws, size_t ws_size,
                              hipStream_t stream) {
  const float* x    = (const float*)d_in[0];
  const float* Wih0 = (const float*)d_in[1];
  const float* Whh0 = (const float*)d_in[2];
  const float* bih0 = (const float*)d_in[3];
  const float* bhh0 = (const float*)d_in[4];
  const float* Wih1 = (const float*)d_in[5];
  const float* Whh1 = (const float*)d_in[6];
  const float* bih1 = (const float*)d_in[7];
  const float* bhh1 = (const float*)d_in[8];
  const float* fcw  = (const float*)d_in[9];
  const float* fcb  = (const float*)d_in[10];
  float* out = (float*)d_out;

  // workspace layout (floats): ~65 MB (ys + second xp pass eliminated)
  float* ws   = (float*)d_ws;
  float* xp   = ws;                         // (2048, 8192) = 16777216 floats
  u64* slots0 = (u64*)(ws + 16777216);      // NREP x 2 x 2048 tagged h0
  u64* slots1 = slots0 + NREP * 2 * H_DIM;  // NREP x 2 x 2048 tagged h1

  dim3 gblk(256);
  dim3 ggrid(H4_DIM / 128, T_LEN / 128);  // (64, 16)

  // layer-0 x-projection: xp = x @ Wih0^T + (bih0+bhh0)
  gemm_bt_bias<<<ggrid, gblk, 0, stream>>>(x, Wih0, bih0, bhh0, xp,
                                           T_LEN, H4_DIM, 512);
  // fused 2-layer pipelined recurrence (2049 rounds)
  lstm_fused<<<256, 512, 0, stream>>>(Whh0, Wih1, Whh1, xp, bih1, bhh1,
                                      slots0, slots1, T_LEN);
  // h1(T) lives at slots1 replica 0, parity (T+1)&1 = 1
  fc_kernel<<<512, 64, 0, stream>>>(slots1 + H_DIM, fcw, fcb, out);
}

// Round 6
// 14137.090 us; speedup vs baseline: 3.0987x; 3.0987x over previous
//
#include <hip/hip_runtime.h>
#include <cstdint>

// Problem constants: D=512, H=2048, T=2048, O=512, 4H=8192.
#define H_DIM 2048
#define H4_DIM 8192
#define T_LEN 2048
#define NREP 8           // slot replicas (per-XCD contention spreading)

typedef unsigned long long u64;
typedef __attribute__((ext_vector_type(2))) float v2f;

__device__ __forceinline__ float sigmoid_f(float x) {
  return 1.0f / (1.0f + __expf(-x));
}
__device__ __forceinline__ float tanh_f(float x) {
  float ax = fabsf(x);
  float e = __expf(-2.0f * ax);
  float r = (1.0f - e) / (1.0f + e);
  return copysignf(r, x);
}

// ---- persistent LSTM recurrence, weights register-resident, NO grid barrier --
// r11 = r5 protocol EXACTLY (tagged-slot poll + s_sleep backoff, two full
// __syncthreads per step, single hl buffer — the only structure that hasn't
// regressed) + ONE change: the per-step x-projection loads are gone.
//   xp is stored TRANSPOSED (8192, T) by the GEMM; each wave prefetches 16
//   steps of its 4 gate rows in ONE coalesced 64-lane load (lane l holds
//   gate l>>4, step t0+(l&15)) and distributes per-step via __shfl.
// WHY: r5's step (2.49us = 6225cy) decomposes as detect ~1800 + compute
// ~1100 + store-visibility ~1000 = ~4000cy; the ~2200cy residual is the
// per-round straggler MAX over 256 blocks. The per-step xp loads (streaming
// 64MB array, occasional ~900cy HBM miss, one slow block stalls the round)
// are the dominant per-block jitter source. Prefetching 16 steps ahead with
// >2000cy of slack removes them from the critical path entirely.
// History: r6 flag-split +hop REGRESS; r7/r8 barrier restructure 2x REGRESS
// (sched_barrier pinning, NOT the sleep — r7==r8); r9 waves_per_eu no-op
// (weights AGPR-parked: 88 arch + 128 acc = 216 <= 256 budget); r10 3-matrix
// fusion: impossible (50.3M floats > 33.5M chip-wide register file).
// Tags 1..2048 never match 0xAAAAAAAA poison; tag loop is the correctness net.
__global__ __launch_bounds__(512, 2) void lstm_rec(
    const float* __restrict__ Whh,   // (8192, 2048)
    const float* __restrict__ xp,    // (8192, T) TRANSPOSED x-proj + biases
    u64* __restrict__ slots,         // NREP * 2 * 2048 tagged h slots
    float* __restrict__ ys,          // (T, 2048) or nullptr
    int T)
{
  __shared__ float hl[H_DIM];
  const int g = blockIdx.x;
  const int tid = threadIdx.x;
  const int w = tid >> 6;
  const int l = tid & 63;
  const int j = g * 8 + w;
  const int rep = g & (NREP - 1);

  // one-time weight load (each element read exactly once grid-wide),
  // packed as float2 for v_pk_fma_f32
  v2f wreg[64];
  #pragma unroll
  for (int q = 0; q < 4; ++q) {
    const float* wr = Whh + (size_t)(j + q * H_DIM) * H_DIM + l * 4;
    #pragma unroll
    for (int k = 0; k < 8; ++k) {
      float4 v = *(const float4*)(wr + 256 * k);
      v2f lo; lo.x = v.x; lo.y = v.y;
      v2f hi; hi.x = v.z; hi.y = v.w;
      wreg[q * 16 + k * 2 + 0] = lo;
      wreg[q * 16 + k * 2 + 1] = hi;
    }
  }

  // per-wave xp prefetch base: lane l covers (gate l>>4, step offset l&15)
  const float* xbase = xp + (size_t)(j + (l >> 4) * H_DIM) * T_LEN + (l & 15);

  float c = 0.0f;
  float pref = 0.0f;

  for (int t = 0; t < T; ++t) {
    // 16-step x-projection prefetch: one coalesced load per wave per 16
    // steps, issued with the whole poll+compute (~>2000cy) as latency slack.
    if ((t & 15) == 0) {
      pref = xbase[t];
    }

    if (t == 0) {
      ((float4*)hl)[tid] = make_float4(0.f, 0.f, 0.f, 0.f);  // h_0 = 0
    } else {
      // consume h_t from my replica: poll with s_sleep backoff (backoff keeps
      // offered LLC load below the congestion knee — r7 lesson)
      const u64* S = slots + ((size_t)(rep * 2 + (t & 1))) * H_DIM + tid;
      u64 v0, v1, v2, v3;
      for (;;) {
        v0 = __hip_atomic_load(S, __ATOMIC_RELAXED, __HIP_MEMORY_SCOPE_AGENT);
        v1 = __hip_atomic_load(S + 512, __ATOMIC_RELAXED, __HIP_MEMORY_SCOPE_AGENT);
        v2 = __hip_atomic_load(S + 1024, __ATOMIC_RELAXED, __HIP_MEMORY_SCOPE_AGENT);
        v3 = __hip_atomic_load(S + 1536, __ATOMIC_RELAXED, __HIP_MEMORY_SCOPE_AGENT);
        bool ok = ((unsigned)(v0 >> 32) == (unsigned)t) &
                  ((unsigned)(v1 >> 32) == (unsigned)t) &
                  ((unsigned)(v2 >> 32) == (unsigned)t) &
                  ((unsigned)(v3 >> 32) == (unsigned)t);
        if (__all(ok)) break;
        __builtin_amdgcn_s_sleep(1);
      }
      hl[tid]        = __uint_as_float((unsigned)v0);
      hl[tid + 512]  = __uint_as_float((unsigned)v1);
      hl[tid + 1024] = __uint_as_float((unsigned)v2);
      hl[tid + 1536] = __uint_as_float((unsigned)v3);
    }
    __syncthreads();

    // packed matvec: 64 v_pk_fma_f32 per thread (4 gates x 16)
    v2f a0 = {0.f, 0.f}, a1 = {0.f, 0.f}, a2 = {0.f, 0.f}, a3 = {0.f, 0.f};
    #pragma unroll
    for (int k = 0; k < 8; ++k) {
      float4 h4 = ((const float4*)hl)[l + 64 * k];
      v2f hlo; hlo.x = h4.x; hlo.y = h4.y;
      v2f hhi; hhi.x = h4.z; hhi.y = h4.w;
      a0 = __builtin_elementwise_fma(wreg[0 + k * 2], hlo, a0);
      a0 = __builtin_elementwise_fma(wreg[1 + k * 2], hhi, a0);
      a1 = __builtin_elementwise_fma(wreg[16 + k * 2], hlo, a1);
      a1 = __builtin_elementwise_fma(wreg[17 + k * 2], hhi, a1);
      a2 = __builtin_elementwise_fma(wreg[32 + k * 2], hlo, a2);
      a2 = __builtin_elementwise_fma(wreg[33 + k * 2], hhi, a2);
      a3 = __builtin_elementwise_fma(wreg[48 + k * 2], hlo, a3);
      a3 = __builtin_elementwise_fma(wreg[49 + k * 2], hhi, a3);
    }
    float acc0 = a0.x + a0.y;
    float acc1 = a1.x + a1.y;
    float acc2 = a2.x + a2.y;
    float acc3 = a3.x + a3.y;

    // 64-lane butterfly ALLreduce (every lane ends with the full 4 dots)
    #pragma unroll
    for (int off = 32; off; off >>= 1) {
      acc0 += __shfl_xor(acc0, off);
      acc1 += __shfl_xor(acc1, off);
      acc2 += __shfl_xor(acc2, off);
      acc3 += __shfl_xor(acc3, off);
    }

    // distribute this step's x-projection from the 16-step prefetch register
    const int dt = t & 15;
    float xq0 = __shfl(pref, dt);
    float xq1 = __shfl(pref, 16 + dt);
    float xq2 = __shfl(pref, 32 + dt);
    float xq3 = __shfl(pref, 48 + dt);

    // gates on all lanes (all lanes now hold real xq); lane k<8 publishes to
    // replica k; lane 0 writes ys
    float i_ = sigmoid_f(acc0 + xq0);
    float f_ = sigmoid_f(acc1 + xq1);
    float g_ = tanh_f(acc2 + xq2);
    float o_ = sigmoid_f(acc3 + xq3);
    c = f_ * c + i_ * g_;
    float h_ = o_ * tanh_f(c);

    if (l < NREP) {
      union { float f; unsigned u; } cv;
      cv.f = h_;
      u64 pv = ((u64)(unsigned)(t + 1) << 32) | (u64)cv.u;
      __hip_atomic_store(
          slots + ((size_t)(l * 2 + ((t + 1) & 1))) * H_DIM + j, pv,
          __ATOMIC_RELAXED, __HIP_MEMORY_SCOPE_AGENT);
      if (l == 0 && ys) ys[(size_t)t * H_DIM + j] = h_;
    }
    // all waves must finish reading hl before next step's poll overwrites it
    __syncthreads();
  }
}

// ---- fp32 GEMM, TRANSPOSED output: Ct[n][m] = A[m]·W[n] + b0[n] + b1[n] ----
// 128x128 tile, 256 threads, 8x8 microtile, BK=8. Ct is (N, M).
__global__ __launch_bounds__(256) void gemm_bt_bias_T(
    const float* __restrict__ A, const float* __restrict__ W,
    const float* __restrict__ b0, const float* __restrict__ b1,
    float* __restrict__ Ct, int M, int N, int K)
{
  __shared__ float As[8][128];
  __shared__ float Bs[8][128];
  const int tid = threadIdx.x;
  const int n0 = blockIdx.x * 128;
  const int m0 = blockIdx.y * 128;
  const int tx = tid & 15;   // n direction
  const int ty = tid >> 4;   // m direction
  const int lr = tid >> 1;   // loader row 0..127
  const int lk = (tid & 1) * 4;
  const float* Ap = A + (size_t)(m0 + lr) * K + lk;
  const float* Wp = W + (size_t)(n0 + lr) * K + lk;

  float acc[8][8];
  #pragma unroll
  for (int i = 0; i < 8; ++i)
    #pragma unroll
    for (int jj = 0; jj < 8; ++jj) acc[i][jj] = 0.f;

  for (int kt = 0; kt < K; kt += 8) {
    float4 av = *(const float4*)(Ap + kt);
    float4 wv = *(const float4*)(Wp + kt);
    __syncthreads();
    As[lk + 0][lr] = av.x; As[lk + 1][lr] = av.y;
    As[lk + 2][lr] = av.z; As[lk + 3][lr] = av.w;
    Bs[lk + 0][lr] = wv.x; Bs[lk + 1][lr] = wv.y;
    Bs[lk + 2][lr] = wv.z; Bs[lk + 3][lr] = wv.w;
    __syncthreads();
    #pragma unroll
    for (int k = 0; k < 8; ++k) {
      float a[8], b[8];
      *(float4*)&a[0] = *(const float4*)&As[k][ty * 8];
      *(float4*)&a[4] = *(const float4*)&As[k][ty * 8 + 4];
      *(float4*)&b[0] = *(const float4*)&Bs[k][tx * 8];
      *(float4*)&b[4] = *(const float4*)&Bs[k][tx * 8 + 4];
      #pragma unroll
      for (int i = 0; i < 8; ++i)
        #pragma unroll
        for (int jj = 0; jj < 8; ++jj)
          acc[i][jj] = fmaf(a[i], b[jj], acc[i][jj]);
    }
  }

  const int n = n0 + tx * 8;
  const int m = m0 + ty * 8;
  #pragma unroll
  for (int jj = 0; jj < 8; ++jj) {
    const float bias = b0[n + jj] + (b1 ? b1[n + jj] : 0.f);
    float* crow = Ct + (size_t)(n + jj) * M + m;
    float4 v0 = make_float4(acc[0][jj] + bias, acc[1][jj] + bias,
                            acc[2][jj] + bias, acc[3][jj] + bias);
    float4 v1 = make_float4(acc[4][jj] + bias, acc[5][jj] + bias,
                            acc[6][jj] + bias, acc[7][jj] + bias);
    *(float4*)crow = v0;
    *(float4*)(crow + 4) = v1;
  }
}

// ---- final FC: out[o] = dot(h_last, fc_w[o]) + fc_b[o], one wave/output ----
// h_last read from layer-1 tagged slots, replica 0, parity 0 (tag T).
__global__ void fc_kernel(const u64* __restrict__ hslots,
                          const float* __restrict__ Wf,
                          const float* __restrict__ bf,
                          float* __restrict__ out)
{
  const int o = blockIdx.x;
  const int l = threadIdx.x;
  const float* wr = Wf + (size_t)o * H_DIM;
  float s = 0.f;
  #pragma unroll
  for (int k = 0; k < 32; ++k) {
    union { unsigned u; float f; } cv;
    cv.u = (unsigned)hslots[l + 64 * k];
    s = fmaf(wr[l + 64 * k], cv.f, s);
  }
  #pragma unroll
  for (int off = 32; off; off >>= 1) s += __shfl_xor(s, off);
  if (l == 0) out[o] = s + bf[o];
}

extern "C" void kernel_launch(void* const* d_in, const int* in_sizes, int n_in,
                              void* d_out, int out_size, void* d_ws, size_t ws_size,
                              hipStream_t stream) {
  const float* x    = (const float*)d_in[0];
  const float* Wih0 = (const float*)d_in[1];
  const float* Whh0 = (const float*)d_in[2];
  const float* bih0 = (const float*)d_in[3];
  const float* bhh0 = (const float*)d_in[4];
  const float* Wih1 = (const float*)d_in[5];
  const float* Whh1 = (const float*)d_in[6];
  const float* bih1 = (const float*)d_in[7];
  const float* bhh1 = (const float*)d_in[8];
  const float* fcw  = (const float*)d_in[9];
  const float* fcb  = (const float*)d_in[10];
  float* out = (float*)d_out;

  // workspace layout (floats): ~85 MB
  float* ws   = (float*)d_ws;
  float* xp   = ws;                      // (8192, 2048) TRANSPOSED = 16777216
  float* ys   = ws + 16777216;           // (2048, 2048) =  4194304
  u64* slots0 = (u64*)(ws + 20971520);   // NREP x 2 x 2048 tagged h (256 KB)
  u64* slots1 = slots0 + NREP * 2 * H_DIM;  // layer 1 (fresh poison)

  dim3 gblk(256);
  dim3 ggrid(H4_DIM / 128, T_LEN / 128);  // (64, 16)

  // layer 0: xp^T = (x @ Wih0^T + bih0+bhh0)^T; recurrence -> ys
  gemm_bt_bias_T<<<ggrid, gblk, 0, stream>>>(x, Wih0, bih0, bhh0, xp,
                                             T_LEN, H4_DIM, 512);
  lstm_rec<<<256, 512, 0, stream>>>(Whh0, xp, slots0, ys, T_LEN);

  // layer 1: xp^T = (ys @ Wih1^T + bih1+bhh1)^T; recurrence, keep only h_last
  gemm_bt_bias_T<<<ggrid, gblk, 0, stream>>>(ys, Wih1, bih1, bhh1, xp,
                                             T_LEN, H4_DIM, H_DIM);
  lstm_rec<<<256, 512, 0, stream>>>(Whh1, xp, slots1, nullptr, T_LEN);

  // h_last of layer 1: slots1 replica 0, parity (T&1)=0, tag T
  fc_kernel<<<512, 64, 0, stream>>>(slots1, fcw, fcb, out);
}

// Round 7
// 10688.635 us; speedup vs baseline: 4.0984x; 1.3226x over previous
//
#include <hip/hip_runtime.h>
#include <cstdint>

// Problem constants: D=512, H=2048, T=2048, O=512, 4H=8192.
#define H_DIM 2048
#define H4_DIM 8192
#define T_LEN 2048
#define NREP 8           // slot replicas (per-XCD contention spreading)

typedef unsigned long long u64;
typedef __attribute__((ext_vector_type(2))) float v2f;

__device__ __forceinline__ float sigmoid_f(float x) {
  return 1.0f / (1.0f + __expf(-x));
}
__device__ __forceinline__ float tanh_f(float x) {
  float ax = fabsf(x);
  float e = __expf(-2.0f * ax);
  float r = (1.0f - e) / (1.0f + e);
  return copysignf(r, x);
}

// Canonical gfx9 64-lane sum via DPP (VALU, ~100cy) instead of the shfl_xor
// butterfly (24 ds-pipe ops, ~300-400cy). Result returned wave-uniform via
// readlane(63). Sequence: row_shr 1/2/4/8 (row sums in lanes 15/31/47/63),
// row_bcast15 (lane31+=lane15, lane63+=lane47), row_bcast31 (lane63+=lane31).
__device__ __forceinline__ float dpp_wave_sum(float x) {
  float f = x;
#define DPP_ADD(ctrl)                                                        \
  f += __builtin_bit_cast(float, __builtin_amdgcn_update_dpp(                \
           0, __builtin_bit_cast(int, f), (ctrl), 0xf, 0xf, true))
  DPP_ADD(0x111);  // row_shr:1
  DPP_ADD(0x112);  // row_shr:2
  DPP_ADD(0x114);  // row_shr:4
  DPP_ADD(0x118);  // row_shr:8
  DPP_ADD(0x142);  // row_bcast:15
  DPP_ADD(0x143);  // row_bcast:31
#undef DPP_ADD
  return __builtin_bit_cast(
      float, __builtin_amdgcn_readlane(__builtin_bit_cast(int, f), 63));
}

// ---- persistent LSTM recurrence, weights register-resident, NO grid barrier --
// r12 = r5 protocol EXACTLY (tagged-slot poll + s_sleep(1) backoff, per-step
// xq loads on lanes 0..7, two full __syncthreads per step, single hl buffer,
// xp in (T,8192) layout) + ONE local change: shfl_xor butterfly -> DPP sum.
// WHY: 6 structural perturbations all regressed or tied —
//   r6 flag/data split: +1 LLC hop (+1050cy/step). r7 unthrottled poll:
//   fabric congestion collapse (FETCH 2x). r8: confirmed structure not sleep.
//   r9 waves_per_eu: no-op (weights AGPR-parked, 88 arch + 128 acc).
//   r10 2-layer fusion: weights exceed chip register file. r11 xp-transpose
//   prefetch: 16MB power-of-2 stride channel aliasing + same-step consume.
// The exchange (publish->MALL visibility->poll detect) is the floor; the only
// untouched serial segment is reduce->gates->publish inside the step. DPP
// cuts ~250cy there without touching any memory access or protocol ordering.
// Tags 1..2048 never match 0xAAAAAAAA poison; tag loop is the correctness net.
__global__ __launch_bounds__(512, 2) void lstm_rec(
    const float* __restrict__ Whh,   // (8192, 2048)
    const float* __restrict__ xp,    // (T, 8192) x-projection + biases
    u64* __restrict__ slots,         // NREP * 2 * 2048 tagged h slots
    float* __restrict__ ys,          // (T, 2048) or nullptr
    int T)
{
  __shared__ float hl[H_DIM];
  const int g = blockIdx.x;
  const int tid = threadIdx.x;
  const int w = tid >> 6;
  const int l = tid & 63;
  const int j = g * 8 + w;
  const int rep = g & (NREP - 1);

  // one-time weight load (each element read exactly once grid-wide),
  // packed as float2 for v_pk_fma_f32
  v2f wreg[64];
  #pragma unroll
  for (int q = 0; q < 4; ++q) {
    const float* wr = Whh + (size_t)(j + q * H_DIM) * H_DIM + l * 4;
    #pragma unroll
    for (int k = 0; k < 8; ++k) {
      float4 v = *(const float4*)(wr + 256 * k);
      v2f lo; lo.x = v.x; lo.y = v.y;
      v2f hi; hi.x = v.z; hi.y = v.w;
      wreg[q * 16 + k * 2 + 0] = lo;
      wreg[q * 16 + k * 2 + 1] = hi;
    }
  }

  float c = 0.0f;

  for (int t = 0; t < T; ++t) {
    // prefetch this step's x-projection early (lanes 0..7, same 4 addresses:
    // broadcast lines; drained under the poll's vmcnt waits)
    float xq0 = 0.f, xq1 = 0.f, xq2 = 0.f, xq3 = 0.f;
    if (l < NREP) {
      const float* xrow = xp + (size_t)t * H4_DIM + j;
      xq0 = xrow[0];
      xq1 = xrow[H_DIM];
      xq2 = xrow[2 * H_DIM];
      xq3 = xrow[3 * H_DIM];
    }

    if (t == 0) {
      ((float4*)hl)[tid] = make_float4(0.f, 0.f, 0.f, 0.f);  // h_0 = 0
    } else {
      // consume h_t from my replica: poll with s_sleep backoff (backoff keeps
      // offered LLC load below the congestion knee — r7 lesson)
      const u64* S = slots + ((size_t)(rep * 2 + (t & 1))) * H_DIM + tid;
      u64 v0, v1, v2, v3;
      for (;;) {
        v0 = __hip_atomic_load(S, __ATOMIC_RELAXED, __HIP_MEMORY_SCOPE_AGENT);
        v1 = __hip_atomic_load(S + 512, __ATOMIC_RELAXED, __HIP_MEMORY_SCOPE_AGENT);
        v2 = __hip_atomic_load(S + 1024, __ATOMIC_RELAXED, __HIP_MEMORY_SCOPE_AGENT);
        v3 = __hip_atomic_load(S + 1536, __ATOMIC_RELAXED, __HIP_MEMORY_SCOPE_AGENT);
        bool ok = ((unsigned)(v0 >> 32) == (unsigned)t) &
                  ((unsigned)(v1 >> 32) == (unsigned)t) &
                  ((unsigned)(v2 >> 32) == (unsigned)t) &
                  ((unsigned)(v3 >> 32) == (unsigned)t);
        if (__all(ok)) break;
        __builtin_amdgcn_s_sleep(1);
      }
      hl[tid]        = __uint_as_float((unsigned)v0);
      hl[tid + 512]  = __uint_as_float((unsigned)v1);
      hl[tid + 1024] = __uint_as_float((unsigned)v2);
      hl[tid + 1536] = __uint_as_float((unsigned)v3);
    }
    __syncthreads();

    // packed matvec: 64 v_pk_fma_f32 per thread (4 gates x 16)
    v2f a0 = {0.f, 0.f}, a1 = {0.f, 0.f}, a2 = {0.f, 0.f}, a3 = {0.f, 0.f};
    #pragma unroll
    for (int k = 0; k < 8; ++k) {
      float4 h4 = ((const float4*)hl)[l + 64 * k];
      v2f hlo; hlo.x = h4.x; hlo.y = h4.y;
      v2f hhi; hhi.x = h4.z; hhi.y = h4.w;
      a0 = __builtin_elementwise_fma(wreg[0 + k * 2], hlo, a0);
      a0 = __builtin_elementwise_fma(wreg[1 + k * 2], hhi, a0);
      a1 = __builtin_elementwise_fma(wreg[16 + k * 2], hlo, a1);
      a1 = __builtin_elementwise_fma(wreg[17 + k * 2], hhi, a1);
      a2 = __builtin_elementwise_fma(wreg[32 + k * 2], hlo, a2);
      a2 = __builtin_elementwise_fma(wreg[33 + k * 2], hhi, a2);
      a3 = __builtin_elementwise_fma(wreg[48 + k * 2], hlo, a3);
      a3 = __builtin_elementwise_fma(wreg[49 + k * 2], hhi, a3);
    }

    // 64-lane sum via DPP (VALU pipe), wave-uniform result on all lanes
    float acc0 = dpp_wave_sum(a0.x + a0.y);
    float acc1 = dpp_wave_sum(a1.x + a1.y);
    float acc2 = dpp_wave_sum(a2.x + a2.y);
    float acc3 = dpp_wave_sum(a3.x + a3.y);

    // gates (uniform dot + per-lane xq; real xq on lanes 0..7, which publish)
    float i_ = sigmoid_f(acc0 + xq0);
    float f_ = sigmoid_f(acc1 + xq1);
    float g_ = tanh_f(acc2 + xq2);
    float o_ = sigmoid_f(acc3 + xq3);
    c = f_ * c + i_ * g_;
    float h_ = o_ * tanh_f(c);

    if (l < NREP) {
      union { float f; unsigned u; } cv;
      cv.f = h_;
      u64 pv = ((u64)(unsigned)(t + 1) << 32) | (u64)cv.u;
      __hip_atomic_store(
          slots + ((size_t)(l * 2 + ((t + 1) & 1))) * H_DIM + j, pv,
          __ATOMIC_RELAXED, __HIP_MEMORY_SCOPE_AGENT);
      if (l == 0 && ys) ys[(size_t)t * H_DIM + j] = h_;
    }
    // all waves must finish reading hl before next step's poll overwrites it
    __syncthreads();
  }
}

// ---- fp32 GEMM: C[M][N] = A[M][K] @ W[N][K]^T + b0[n] + b1[n] ----
// 128x128 tile, 256 threads, 8x8 microtile, BK=8.
__global__ __launch_bounds__(256) void gemm_bt_bias(
    const float* __restrict__ A, const float* __restrict__ W,
    const float* __restrict__ b0, const float* __restrict__ b1,
    float* __restrict__ C, int M, int N, int K)
{
  __shared__ float As[8][128];
  __shared__ float Bs[8][128];
  const int tid = threadIdx.x;
  const int n0 = blockIdx.x * 128;
  const int m0 = blockIdx.y * 128;
  const int tx = tid & 15;   // n direction
  const int ty = tid >> 4;   // m direction
  const int lr = tid >> 1;   // loader row 0..127
  const int lk = (tid & 1) * 4;
  const float* Ap = A + (size_t)(m0 + lr) * K + lk;
  const float* Wp = W + (size_t)(n0 + lr) * K + lk;

  float acc[8][8];
  #pragma unroll
  for (int i = 0; i < 8; ++i)
    #pragma unroll
    for (int jj = 0; jj < 8; ++jj) acc[i][jj] = 0.f;

  for (int kt = 0; kt < K; kt += 8) {
    float4 av = *(const float4*)(Ap + kt);
    float4 wv = *(const float4*)(Wp + kt);
    __syncthreads();
    As[lk + 0][lr] = av.x; As[lk + 1][lr] = av.y;
    As[lk + 2][lr] = av.z; As[lk + 3][lr] = av.w;
    Bs[lk + 0][lr] = wv.x; Bs[lk + 1][lr] = wv.y;
    Bs[lk + 2][lr] = wv.z; Bs[lk + 3][lr] = wv.w;
    __syncthreads();
    #pragma unroll
    for (int k = 0; k < 8; ++k) {
      float a[8], b[8];
      *(float4*)&a[0] = *(const float4*)&As[k][ty * 8];
      *(float4*)&a[4] = *(const float4*)&As[k][ty * 8 + 4];
      *(float4*)&b[0] = *(const float4*)&Bs[k][tx * 8];
      *(float4*)&b[4] = *(const float4*)&Bs[k][tx * 8 + 4];
      #pragma unroll
      for (int i = 0; i < 8; ++i)
        #pragma unroll
        for (int jj = 0; jj < 8; ++jj)
          acc[i][jj] = fmaf(a[i], b[jj], acc[i][jj]);
    }
  }

  const int n = n0 + tx * 8;
  float bias[8];
  #pragma unroll
  for (int jj = 0; jj < 8; ++jj)
    bias[jj] = b0[n + jj] + (b1 ? b1[n + jj] : 0.f);
  #pragma unroll
  for (int i = 0; i < 8; ++i) {
    float* crow = C + (size_t)(m0 + ty * 8 + i) * N + n;
    float4 v0 = make_float4(acc[i][0] + bias[0], acc[i][1] + bias[1],
                            acc[i][2] + bias[2], acc[i][3] + bias[3]);
    float4 v1 = make_float4(acc[i][4] + bias[4], acc[i][5] + bias[5],
                            acc[i][6] + bias[6], acc[i][7] + bias[7]);
    *(float4*)crow = v0;
    *(float4*)(crow + 4) = v1;
  }
}

// ---- final FC: out[o] = dot(h_last, fc_w[o]) + fc_b[o], one wave/output ----
// h_last read from layer-1 tagged slots, replica 0, parity 0 (tag T).
__global__ void fc_kernel(const u64* __restrict__ hslots,
                          const float* __restrict__ Wf,
                          const float* __restrict__ bf,
                          float* __restrict__ out)
{
  const int o = blockIdx.x;
  const int l = threadIdx.x;
  const float* wr = Wf + (size_t)o * H_DIM;
  float s = 0.f;
  #pragma unroll
  for (int k = 0; k < 32; ++k) {
    union { unsigned u; float f; } cv;
    cv.u = (unsigned)hslots[l + 64 * k];
    s = fmaf(wr[l + 64 * k], cv.f, s);
  }
  #pragma unroll
  for (int off = 32; off; off >>= 1) s += __shfl_xor(s, off);
  if (l == 0) out[o] = s + bf[o];
}

extern "C" void kernel_launch(void* const* d_in, const int* in_sizes, int n_in,
                              void* d_out, int out_size, void* d_ws, size_t ws_size,
                              hipStream_t stream) {
  const float* x    = (const float*)d_in[0];
  const float* Wih0 = (const float*)d_in[1];
  const float* Whh0 = (const float*)d_in[2];
  const float* bih0 = (const float*)d_in[3];
  const float* bhh0 = (const float*)d_in[4];
  const float* Wih1 = (const float*)d_in[5];
  const float* Whh1 = (const float*)d_in[6];
  const float* bih1 = (const float*)d_in[7];
  const float* bhh1 = (const float*)d_in[8];
  const float* fcw  = (const float*)d_in[9];
  const float* fcb  = (const float*)d_in[10];
  float* out = (float*)d_out;

  // workspace layout (floats): ~85 MB
  float* ws   = (float*)d_ws;
  float* xp   = ws;                      // (2048, 8192) = 16777216
  float* ys   = ws + 16777216;           // (2048, 2048) =  4194304
  u64* slots0 = (u64*)(ws + 20971520);   // NREP x 2 x 2048 tagged h (256 KB)
  u64* slots1 = slots0 + NREP * 2 * H_DIM;  // layer 1 (fresh poison)

  dim3 gblk(256);
  dim3 ggrid(H4_DIM / 128, T_LEN / 128);  // (64, 16)

  // layer 0: xp = x @ Wih0^T + (bih0+bhh0); recurrence -> ys
  gemm_bt_bias<<<ggrid, gblk, 0, stream>>>(x, Wih0, bih0, bhh0, xp,
                                           T_LEN, H4_DIM, 512);
  lstm_rec<<<256, 512, 0, stream>>>(Whh0, xp, slots0, ys, T_LEN);

  // layer 1: xp = ys @ Wih1^T + (bih1+bhh1); recurrence, keep only h_last
  gemm_bt_bias<<<ggrid, gblk, 0, stream>>>(ys, Wih1, bih1, bhh1, xp,
                                           T_LEN, H4_DIM, H_DIM);
  lstm_rec<<<256, 512, 0, stream>>>(Whh1, xp, slots1, nullptr, T_LEN);

  // h_last of layer 1: slots1 replica 0, parity (T&1)=0, tag T
  fc_kernel<<<512, 64, 0, stream>>>(slots1, fcw, fcb, out);
}